// Round 3
// baseline (1887.639 us; speedup 1.0000x reference)
//
#include <hip/hip_runtime.h>
#include <stdint.h>
#include <stddef.h>

typedef unsigned short u16t;
typedef unsigned int   u32t;
typedef __bf16  bf16x8 __attribute__((ext_vector_type(8)));
typedef float   f32x4  __attribute__((ext_vector_type(4)));

#define NN 50000
#define NE 800000
#define NG 16
#define DD 64
#define HH 128

#define AS 264   // edge A-strip row stride (256+8): row step = 132 words -> +4 banks/row
#define HS 136   // h-strip row stride (128+8): row step = 68 words -> +4 banks/row
#define NAS 200  // node A-strip stride (192+8): 100 words -> +4 banks/row
#define ES 68    // sEagg group stride: g*68 words -> +4 banks/group (kills quad conflicts)

static __device__ __forceinline__ float bf2f(u16t h){
  return __uint_as_float(((u32t)h) << 16);
}
static __device__ __forceinline__ u16t f2bf(float f){
  u32t u = __float_as_uint(f);
  u32t r = u + 0x7FFFu + ((u >> 16) & 1u);   // RNE
  return (u16t)(r >> 16);
}
static __device__ __forceinline__ u32t pk2(float a, float b){
  return (u32t)f2bf(a) | ((u32t)f2bf(b) << 16);
}
static __device__ __forceinline__ bf16x8 ldfrag(const u16t* p){
  return __builtin_bit_cast(bf16x8, *(const uint4*)p);
}
// compiler fence: LDS is in-order per wave, so cross-lane RAW/WAR within a wave
// only needs the compiler not to reorder ds ops across this point.
static __device__ __forceinline__ void wavefence(){
  asm volatile("" ::: "memory");
  __builtin_amdgcn_wave_barrier();
  asm volatile("" ::: "memory");
}

// load 16 consecutive logical elements (fp32 or bf16 array) -> 16 bf16 into LDS
static __device__ __forceinline__ void stage16(u16t* dst, const void* src, size_t eoff, bool f32){
  if (!f32){
    const u16t* p = (const u16t*)src + eoff;
    *(uint4*)(dst)     = *(const uint4*)(p);
    *(uint4*)(dst + 8) = *(const uint4*)(p + 8);
  } else {
    const float* p = (const float*)src + eoff;
    u32t* d32 = (u32t*)dst;
    #pragma unroll
    for (int j = 0; j < 4; ++j){
      float4 v = *(const float4*)(p + 4*j);
      d32[2*j]   = pk2(v.x, v.y);
      d32[2*j+1] = pk2(v.z, v.w);
    }
  }
}
static __device__ __forceinline__ float ldb(const void* b, int i, bool f32){
  return f32 ? ((const float*)b)[i] : bf2f(((const u16t*)b)[i]);
}
static __device__ __forceinline__ void store1(void* out, size_t idx, float v, bool f32){
  if (f32) ((float*)out)[idx] = v;
  else     ((u16t*)out)[idx]  = f2bf(v);
}

// One dispatch: dtype-detect (per block, from x) + repack all 6 weight matrices
// into MFMA-B-fragment order: Wp[((kk*Ncols+n)*32)+t] = W[kk*32+t][n].
__global__ __launch_bounds__(256) void repack_all(
  const void* We1, const void* We2, const void* Wa1, const void* Wa2,
  const void* Wn1, const void* Wn2, const void* x,
  u16t* Wp_e1, u16t* Wp_e2, u16t* Wp_a1, u16t* Wp_a2, u16t* Wp_n1, u16t* Wp_n2,
  int* flag)
{
  __shared__ int sF;
  if (threadIdx.x == 0){
    const u16t* xh = (const u16t*)x;
    int bad = 0;
    for (int i = 0; i < 256; ++i){
      float a = fabsf(bf2f(xh[i]));
      if (!(a > 1e-6f && a < 1e4f)) bad++;   // NaN lands here too
    }
    sF = (bad > 32) ? 1 : 0;
    if (blockIdx.x == 0) *flag = sF;
  }
  __syncthreads();
  const bool f32 = (sF != 0);
  int b = blockIdx.x;
  const void* W; u16t* Wp; int K, Ncols, idx0;
  if      (b < 128){ W = We1; Wp = Wp_e1; K = 256; Ncols = 128; idx0 = b * 256; }
  else if (b < 160){ W = We2; Wp = Wp_e2; K = 128; Ncols = 64;  idx0 = (b-128) * 256; }
  else if (b < 288){ W = Wa1; Wp = Wp_a1; K = 256; Ncols = 128; idx0 = (b-160) * 256; }
  else if (b < 320){ W = Wa2; Wp = Wp_a2; K = 128; Ncols = 64;  idx0 = (b-288) * 256; }
  else if (b < 416){ W = Wn1; Wp = Wp_n1; K = 192; Ncols = 128; idx0 = (b-320) * 256; }
  else             { W = Wn2; Wp = Wp_n2; K = 128; Ncols = 64;  idx0 = (b-416) * 256; }
  int idx = idx0 + threadIdx.x;
  if (idx >= K * Ncols) return;
  int per = Ncols * 32;
  int kk  = idx / per;
  int rem = idx - kk * per;
  int n   = rem >> 5;
  int t   = rem & 31;
  int src = (kk * 32 + t) * Ncols + n;
  float v = f32 ? ((const float*)W)[src] : bf2f(((const u16t*)W)[src]);
  Wp[idx] = f2bf(v);
}

// Barrier-free edge kernel: each WAVE independently processes 16-edge strips.
// 128 threads = 2 waves/block; LDS ~29.5KB -> 5 blocks/CU = 10 waves/CU.
__global__ __launch_bounds__(128) void edge_kernel(
  const void* __restrict__ x, const int* __restrict__ ei, const void* __restrict__ e,
  const void* __restrict__ u, const int* __restrict__ batch,
  const u16t* __restrict__ Wp1, const void* __restrict__ b1,
  const u16t* __restrict__ Wp2, const void* __restrict__ b2,
  const u16t* __restrict__ WpA1, const void* __restrict__ ba1,
  const u16t* __restrict__ WpA2, const void* __restrict__ ba2,
  void* __restrict__ d_out, float* __restrict__ agg, float* __restrict__ edge_agg,
  const int* __restrict__ flag)
{
  __shared__ u16t  sA[2][16 * AS];
  __shared__ u16t  sH[2][16 * HS];
  __shared__ float sEagg[NG * ES];
  __shared__ int   sDst[2][16];
  __shared__ int   sG[2][16];

  const bool f32 = (*flag != 0);
  const size_t OUT_E = (size_t)NN * DD;

  const int tid  = threadIdx.x;
  const int w    = tid >> 6;
  const int lane = tid & 63;
  const int l15  = lane & 15;
  const int quad = lane >> 4;
  const int el   = lane >> 2;   // strip-local edge 0..15 (4 lanes/edge)
  const int q    = lane & 3;    // 16-col chunk

  for (int i = tid; i < NG * ES; i += 128) sEagg[i] = 0.f;
  __syncthreads();   // the only block barrier before the final flush

  u16t* mA = sA[w];
  u16t* mH = sH[w];
  int*  mD = sDst[w];
  int*  mG = sG[w];
  const int wb = (l15 << 5) + quad * 8;   // B-fragment lane offset
  const f32x4 vzero = {0.f, 0.f, 0.f, 0.f};

  const int nw = gridDim.x * 2;
  for (int strip = blockIdx.x * 2 + w; strip < NE / 16; strip += nw){
    const int base = strip * 16;

    // ---- stage [xs | xd | e | u_src] 16 x 256 bf16 (wave-local rows) ----
    {
      const int eidx = base + el;
      const int s = ei[eidx];
      const int d = ei[NE + eidx];
      if (q == 0){ mD[el] = d; mG[el] = batch[s]; }
      u16t* row = mA + el * AS + q * 16;
      stage16(row,       x, (size_t)s    * DD + q * 16, f32);
      stage16(row +  64, x, (size_t)d    * DD + q * 16, f32);
      stage16(row + 128, e, (size_t)eidx * DD + q * 16, f32);
      stage16(row + 192, u, (size_t)mG[0] * 0 + (size_t)batch[s] * DD + q * 16, f32);
    }
    wavefence();

    // ---- edge MLP layer 1: [16x256]@[256x128] ----
    f32x4 acc[8];
    #pragma unroll
    for (int ct = 0; ct < 8; ++ct) acc[ct] = vzero;
    for (int kk = 0; kk < 8; ++kk){
      bf16x8 af = ldfrag(&mA[l15 * AS + kk * 32 + quad * 8]);
      #pragma unroll
      for (int ct = 0; ct < 8; ++ct){
        bf16x8 bw = ldfrag(&Wp1[((kk * HH + ct * 16) << 5) + wb]);
        acc[ct] = __builtin_amdgcn_mfma_f32_16x16x32_bf16(af, bw, acc[ct], 0, 0, 0);
      }
    }
    #pragma unroll
    for (int ct = 0; ct < 8; ++ct){
      const int col = ct * 16 + l15;
      const float bias = ldb(b1, col, f32);
      #pragma unroll
      for (int r = 0; r < 4; ++r)
        mH[(quad * 4 + r) * HS + col] = f2bf(fmaxf(acc[ct][r] + bias, 0.f));
    }
    wavefence();

    // ---- edge MLP layer 2: [16x128]@[128x64] -> e_new ----
    f32x4 acc2[4];
    #pragma unroll
    for (int ct = 0; ct < 4; ++ct) acc2[ct] = vzero;
    for (int kk = 0; kk < 4; ++kk){
      bf16x8 af = ldfrag(&mH[l15 * HS + kk * 32 + quad * 8]);
      #pragma unroll
      for (int ct = 0; ct < 4; ++ct){
        bf16x8 bw = ldfrag(&Wp2[((kk * 64 + ct * 16) << 5) + wb]);
        acc2[ct] = __builtin_amdgcn_mfma_f32_16x16x32_bf16(af, bw, acc2[ct], 0, 0, 0);
      }
    }
    float enew[4][4];
    #pragma unroll
    for (int ct = 0; ct < 4; ++ct){
      const int col = ct * 16 + l15;
      const float bias = ldb(b2, col, f32);
      #pragma unroll
      for (int r = 0; r < 4; ++r){
        float v = acc2[ct][r] + bias;
        enew[ct][r] = v;
        const int row = quad * 4 + r;
        store1(d_out, OUT_E + (size_t)(base + row) * DD + col, v, f32);
        mA[row * AS + 128 + col] = f2bf(v);      // e-slot <- e_new
        atomicAdd(&sEagg[mG[row] * ES + col], v);
      }
    }
    wavefence();

    // ---- attention MLP layer 1 ----
    f32x4 acc3[8];
    #pragma unroll
    for (int ct = 0; ct < 8; ++ct) acc3[ct] = vzero;
    for (int kk = 0; kk < 8; ++kk){
      bf16x8 af = ldfrag(&mA[l15 * AS + kk * 32 + quad * 8]);
      #pragma unroll
      for (int ct = 0; ct < 8; ++ct){
        bf16x8 bw = ldfrag(&WpA1[((kk * HH + ct * 16) << 5) + wb]);
        acc3[ct] = __builtin_amdgcn_mfma_f32_16x16x32_bf16(af, bw, acc3[ct], 0, 0, 0);
      }
    }
    #pragma unroll
    for (int ct = 0; ct < 8; ++ct){
      const int col = ct * 16 + l15;
      const float bias = ldb(ba1, col, f32);
      #pragma unroll
      for (int r = 0; r < 4; ++r)
        mH[(quad * 4 + r) * HS + col] = f2bf(fmaxf(acc3[ct][r] + bias, 0.f));
    }
    wavefence();

    // ---- attention MLP layer 2 -> sigmoid -> scatter e_new*a ----
    f32x4 acc4[4];
    #pragma unroll
    for (int ct = 0; ct < 4; ++ct) acc4[ct] = vzero;
    for (int kk = 0; kk < 4; ++kk){
      bf16x8 af = ldfrag(&mH[l15 * HS + kk * 32 + quad * 8]);
      #pragma unroll
      for (int ct = 0; ct < 4; ++ct){
        bf16x8 bw = ldfrag(&WpA2[((kk * 64 + ct * 16) << 5) + wb]);
        acc4[ct] = __builtin_amdgcn_mfma_f32_16x16x32_bf16(af, bw, acc4[ct], 0, 0, 0);
      }
    }
    #pragma unroll
    for (int ct = 0; ct < 4; ++ct){
      const int col = ct * 16 + l15;
      const float bias = ldb(ba2, col, f32);
      #pragma unroll
      for (int r = 0; r < 4; ++r){
        float sv = acc4[ct][r] + bias;
        float av = 1.0f / (1.0f + __expf(-sv));
        const int row = quad * 4 + r;
        atomicAdd(&agg[(size_t)mD[row] * DD + col], enew[ct][r] * av);
      }
    }
    wavefence();   // next strip's staging overwrites mA/mH (in-order LDS per wave)
  }

  __syncthreads();
  for (int i = tid; i < NG * ES; i += 128){
    int g = i / ES, c = i - g * ES;
    if (c < DD) atomicAdd(&edge_agg[g * DD + c], sEagg[i]);
  }
}

// Barrier-free node kernel: wave-owned 16-node strips (3125 strips exactly).
__global__ __launch_bounds__(128) void node_kernel(
  const void* __restrict__ x, const float* __restrict__ agg, const void* __restrict__ u,
  const int* __restrict__ batch,
  const u16t* __restrict__ WpN1, const void* __restrict__ bn1,
  const u16t* __restrict__ WpN2, const void* __restrict__ bn2,
  void* __restrict__ d_out, float* __restrict__ node_agg, const int* __restrict__ flag)
{
  __shared__ u16t  sA[2][16 * NAS];
  __shared__ u16t  sH[2][16 * HS];
  __shared__ float sNagg[NG * ES];
  __shared__ int   sGn[2][16];

  const bool f32 = (*flag != 0);
  const int tid  = threadIdx.x;
  const int w    = tid >> 6;
  const int lane = tid & 63;
  const int l15  = lane & 15;
  const int quad = lane >> 4;
  const int el   = lane >> 2;
  const int q    = lane & 3;

  for (int i = tid; i < NG * ES; i += 128) sNagg[i] = 0.f;
  __syncthreads();

  u16t* mA = sA[w];
  u16t* mH = sH[w];
  int*  mG = sGn[w];
  const int wb = (l15 << 5) + quad * 8;
  const f32x4 vzero = {0.f, 0.f, 0.f, 0.f};

  const int strip = blockIdx.x * 2 + w;
  if (strip < NN / 16){
    const int base = strip * 16;
    // ---- stage [x | agg | u_batch] 16 x 192 ----
    {
      const int n = base + el;
      const int g = batch[n];
      if (q == 0) mG[el] = g;
      u16t* row = mA + el * NAS + q * 16;
      stage16(row, x, (size_t)n * DD + q * 16, f32);
      const float* pa = agg + (size_t)n * DD + q * 16;
      u32t* d32 = (u32t*)(row + 64);
      #pragma unroll
      for (int j = 0; j < 4; ++j){
        float4 v = *(const float4*)(pa + 4 * j);
        d32[2*j]   = pk2(v.x, v.y);
        d32[2*j+1] = pk2(v.z, v.w);
      }
      stage16(row + 128, u, (size_t)g * DD + q * 16, f32);
    }
    wavefence();

    // ---- node MLP layer 1: K=192 ----
    f32x4 acc[8];
    #pragma unroll
    for (int ct = 0; ct < 8; ++ct) acc[ct] = vzero;
    for (int kk = 0; kk < 6; ++kk){
      bf16x8 af = ldfrag(&mA[l15 * NAS + kk * 32 + quad * 8]);
      #pragma unroll
      for (int ct = 0; ct < 8; ++ct){
        bf16x8 bw = ldfrag(&WpN1[((kk * HH + ct * 16) << 5) + wb]);
        acc[ct] = __builtin_amdgcn_mfma_f32_16x16x32_bf16(af, bw, acc[ct], 0, 0, 0);
      }
    }
    #pragma unroll
    for (int ct = 0; ct < 8; ++ct){
      const int col = ct * 16 + l15;
      const float bias = ldb(bn1, col, f32);
      #pragma unroll
      for (int r = 0; r < 4; ++r)
        mH[(quad * 4 + r) * HS + col] = f2bf(fmaxf(acc[ct][r] + bias, 0.f));
    }
    wavefence();

    // ---- node MLP layer 2 -> x_new ----
    f32x4 acc2[4];
    #pragma unroll
    for (int ct = 0; ct < 4; ++ct) acc2[ct] = vzero;
    for (int kk = 0; kk < 4; ++kk){
      bf16x8 af = ldfrag(&mH[l15 * HS + kk * 32 + quad * 8]);
      #pragma unroll
      for (int ct = 0; ct < 4; ++ct){
        bf16x8 bw = ldfrag(&WpN2[((kk * 64 + ct * 16) << 5) + wb]);
        acc2[ct] = __builtin_amdgcn_mfma_f32_16x16x32_bf16(af, bw, acc2[ct], 0, 0, 0);
      }
    }
    #pragma unroll
    for (int ct = 0; ct < 4; ++ct){
      const int col = ct * 16 + l15;
      const float bias = ldb(bn2, col, f32);
      #pragma unroll
      for (int r = 0; r < 4; ++r){
        const int row = quad * 4 + r;
        float v = acc2[ct][r] + bias;
        store1(d_out, (size_t)(base + row) * DD + col, v, f32);
        atomicAdd(&sNagg[mG[row] * ES + col], v);
      }
    }
  }
  __syncthreads();
  for (int i = tid; i < NG * ES; i += 128){
    int g = i / ES, c = i - g * ES;
    if (c < DD) atomicAdd(&node_agg[g * DD + c], sNagg[i]);
  }
}

__global__ __launch_bounds__(128) void global_kernel(
  const void* __restrict__ u, const float* __restrict__ node_agg, const float* __restrict__ edge_agg,
  const void* __restrict__ Wg1, const void* __restrict__ bg1,
  const void* __restrict__ Wg2, const void* __restrict__ bg2,
  void* __restrict__ d_out, const int* __restrict__ flag)
{
  __shared__ float sIn[192];
  __shared__ float sHg[HH];
  const bool f32 = (*flag != 0);
  const size_t OUT_U = (size_t)NN * DD + (size_t)NE * DD;
  const int g = blockIdx.x;
  const int tid = threadIdx.x;
  for (int i = tid; i < 192; i += 128){
    float v;
    if      (i <  64) v = ldb(u, g * 64 + i, f32);
    else if (i < 128) v = node_agg[g * 64 + (i - 64)];
    else              v = edge_agg[g * 64 + (i - 128)];
    sIn[i] = v;
  }
  __syncthreads();
  {
    int j = tid;  // 128 hidden units
    float s = ldb(bg1, j, f32);
    for (int k = 0; k < 192; ++k)
      s += sIn[k] * ldb(Wg1, k * 128 + j, f32);
    sHg[j] = fmaxf(s, 0.f);
  }
  __syncthreads();
  if (tid < 64){
    int j = tid;
    float s = ldb(bg2, j, f32);
    for (int k = 0; k < 128; ++k)
      s += sHg[k] * ldb(Wg2, k * 64 + j, f32);
    store1(d_out, OUT_U + g * 64 + j, s, f32);
  }
}

extern "C" void kernel_launch(void* const* d_in, const int* in_sizes, int n_in,
                              void* d_out, int out_size, void* d_ws, size_t ws_size,
                              hipStream_t stream)
{
  const void* x     = d_in[0];
  const int*  ei    = (const int*)d_in[1];
  const void* e     = d_in[2];
  const void* u     = d_in[3];
  const int*  batch = (const int*)d_in[4];
  const void* We1 = d_in[5];  const void* be1 = d_in[6];
  const void* We2 = d_in[7];  const void* be2 = d_in[8];
  const void* Wa1 = d_in[9];  const void* ba1 = d_in[10];
  const void* Wa2 = d_in[11]; const void* ba2 = d_in[12];
  const void* Wn1 = d_in[13]; const void* bn1 = d_in[14];
  const void* Wn2 = d_in[15]; const void* bn2 = d_in[16];
  const void* Wg1 = d_in[17]; const void* bg1 = d_in[18];
  const void* Wg2 = d_in[19]; const void* bg2 = d_in[20];

  // ws layout: [flag 16B][agg NN*DD f32][edge_agg][node_agg][packed weights]
  int*   flag     = (int*)d_ws;
  float* agg      = (float*)((char*)d_ws + 16);
  float* edge_agg = agg + (size_t)NN * DD;
  float* node_agg = edge_agg + NG * DD;
  u16t*  wp    = (u16t*)(node_agg + NG * DD);
  u16t*  Wp_e1 = wp; wp += 256 * 128;
  u16t*  Wp_e2 = wp; wp += 128 * 64;
  u16t*  Wp_a1 = wp; wp += 256 * 128;
  u16t*  Wp_a2 = wp; wp += 128 * 64;
  u16t*  Wp_n1 = wp; wp += 192 * 128;
  u16t*  Wp_n2 = wp; wp += 128 * 64;

  hipMemsetAsync(agg, 0, ((size_t)NN * DD + 2 * NG * DD) * sizeof(float), stream);

  repack_all<<<448, 256, 0, stream>>>(We1, We2, Wa1, Wa2, Wn1, Wn2, x,
      Wp_e1, Wp_e2, Wp_a1, Wp_a2, Wp_n1, Wp_n2, flag);

  edge_kernel<<<2560, 128, 0, stream>>>(x, ei, e, u, batch,
      Wp_e1, be1, Wp_e2, be2, Wp_a1, ba1, Wp_a2, ba2,
      d_out, agg, edge_agg, flag);

  node_kernel<<<(NN / 16 + 1) / 2, 128, 0, stream>>>(x, agg, u, batch,
      Wp_n1, bn1, Wp_n2, bn2, d_out, node_agg, flag);

  global_kernel<<<NG, 128, 0, stream>>>(u, node_agg, edge_agg,
      Wg1, bg1, Wg2, bg2, d_out, flag);
}